// Round 1
// baseline (635.517 us; speedup 1.0000x reference)
//
#include <hip/hip_runtime.h>
#include <hip/hip_bf16.h>
#include <cstddef>

#define IN_DIM 128
#define MEM 256
#define KTOT 384
#define NLEAF 65536

typedef float f32x4 __attribute__((ext_vector_type(4)));
typedef short s16x8 __attribute__((ext_vector_type(8)));

__device__ inline unsigned short f2bf(float f){
    unsigned int u = __builtin_bit_cast(unsigned int, f);
    u += 0x7fff + ((u >> 16) & 1);
    return (unsigned short)(u >> 16);
}
__device__ inline float bf2f(unsigned short h){
    unsigned int u = ((unsigned int)h) << 16;
    return __builtin_bit_cast(float, u);
}

// ---------------- pack W: Wp[g'][k], g' = m*4 + chunk, k: 0..127 = W_ih, 128..383 = W_hh
__global__ void pack_w_kernel(const float* __restrict__ W_ih, const float* __restrict__ b_ih,
                              const float* __restrict__ W_hh, const float* __restrict__ b_hh,
                              unsigned short* __restrict__ Wp, float* __restrict__ bp){
    int gp = blockIdx.x;              // 0..1023
    int m = gp >> 2, ch = gp & 3;
    int row = ch * 256 + m;
    for (int k = threadIdx.x; k < KTOT; k += blockDim.x){
        float v = (k < IN_DIM) ? W_ih[row * IN_DIM + k] : W_hh[row * MEM + (k - IN_DIM)];
        Wp[gp * KTOT + k] = f2bf(v);
    }
    if (threadIdx.x == 0) bp[gp] = b_ih[row] + b_hh[row];
}

// ---------------- leaf pack: A[j][k<128] = bf16(x_leaf[j][k]), stride 128
__global__ void pack_leaf_kernel(const float* __restrict__ x_l, unsigned short* __restrict__ A){
    int g = blockIdx.x * blockDim.x + threadIdx.x;   // each handles 8 elems
    size_t base = (size_t)g * 8;
    f32x4 v0 = *(const f32x4*)(x_l + base);
    f32x4 v1 = *(const f32x4*)(x_l + base + 4);
    s16x8 o;
    #pragma unroll
    for (int e = 0; e < 4; ++e){ o[e] = (short)f2bf(v0[e]); o[4+e] = (short)f2bf(v1[e]); }
    *(s16x8*)(A + base) = o;
}

// ---------------- non-leaf pack: A[j][0..127]=x, A[j][128+k]=h_below[2j][k]+h_below[2j+1][k], stride 384
__global__ void pack_level_kernel(int n, const float* __restrict__ x_l,
                                  const unsigned short* __restrict__ h_below,
                                  unsigned short* __restrict__ A){
    int total_x = n * IN_DIM / 8;
    int total_h = n * MEM / 8;
    int total = total_x + total_h;
    for (int g = blockIdx.x * blockDim.x + threadIdx.x; g < total; g += gridDim.x * blockDim.x){
        if (g < total_x){
            int j = g >> 4;             // 16 groups of 8 per 128-wide row
            int ko = (g & 15) * 8;
            const f32x4* s = (const f32x4*)(x_l + (size_t)j * IN_DIM + ko);
            f32x4 v0 = s[0], v1 = s[1];
            s16x8 o;
            #pragma unroll
            for (int e = 0; e < 4; ++e){ o[e] = (short)f2bf(v0[e]); o[4+e] = (short)f2bf(v1[e]); }
            *(s16x8*)(A + (size_t)j * KTOT + ko) = o;
        } else {
            int gh = g - total_x;
            int j = gh >> 5;            // 32 groups of 8 per 256-wide row
            int ko = (gh & 31) * 8;
            s16x8 ha = *(const s16x8*)(h_below + (size_t)(2*j) * MEM + ko);
            s16x8 hb = *(const s16x8*)(h_below + (size_t)(2*j+1) * MEM + ko);
            s16x8 o;
            #pragma unroll
            for (int e = 0; e < 8; ++e)
                o[e] = (short)f2bf(bf2f((unsigned short)ha[e]) + bf2f((unsigned short)hb[e]));
            *(s16x8*)(A + (size_t)j * KTOT + IN_DIM + ko) = o;
        }
    }
}

// ---------------- fused GEMM + LSTM epilogue
// gates'[j][g'] = sum_k A[j][k] * Wp[g'][k];  g' = 4m+chunk (i,f,g,o)
#define BM 64
#define BN 128
#define KC 64
#define PA 72
#define PB 72

__global__ __launch_bounds__(256, 2) void gemm_lstm_kernel(
    const unsigned short* __restrict__ A, int lda, int n, int nK,
    const unsigned short* __restrict__ Wp, const float* __restrict__ bp,
    const float* __restrict__ c_below, int leaf,
    float* __restrict__ c_out, unsigned short* __restrict__ h_out)
{
    __shared__ __align__(16) char smem[55296];
    unsigned short* As = (unsigned short*)smem;              // [2][64][72]
    unsigned short* Bs = (unsigned short*)(smem + 18432);    // [2][128][72]
    float* gsm = (float*)smem;                               // [64][132] (reused after K-loop)

    const int tid  = threadIdx.x;
    const int lane = tid & 63;
    const int wid  = tid >> 6;
    const int row0 = blockIdx.x * BM;
    const int col0 = blockIdx.y * BN;

    f32x4 acc[4][2];
    #pragma unroll
    for (int r = 0; r < 4; ++r)
        #pragma unroll
        for (int q = 0; q < 2; ++q)
            acc[r][q] = (f32x4){0.f, 0.f, 0.f, 0.f};

    const int nIter = nK / KC;

    auto stage = [&](int d, int kk){
        const unsigned short* Ag = A + (size_t)row0 * lda + kk;
        #pragma unroll
        for (int c = tid; c < 512; c += 256){
            int ar = c >> 3, ac = (c & 7) * 8;
            f32x4 v = *(const f32x4*)(Ag + (size_t)ar * lda + ac);
            *(f32x4*)(As + d * 64 * PA + ar * PA + ac) = v;
        }
        const unsigned short* Bg = Wp + (size_t)col0 * KTOT + kk;
        #pragma unroll
        for (int c = tid; c < 1024; c += 256){
            int br = c >> 3, bc = (c & 7) * 8;
            f32x4 v = *(const f32x4*)(Bg + (size_t)br * KTOT + bc);
            *(f32x4*)(Bs + d * 128 * PB + br * PB + bc) = v;
        }
    };

    stage(0, 0);
    int buf = 0, kk = 0;
    for (int it = 0; it < nIter; ++it){
        __syncthreads();
        if (it + 1 < nIter) stage(buf ^ 1, kk + KC);
        const unsigned short* Ab = As + buf * 64 * PA;
        const unsigned short* Bb = Bs + buf * 128 * PB;
        #pragma unroll
        for (int ks = 0; ks < 2; ++ks){
            int kb = ks * 32 + (lane >> 4) * 8;
            s16x8 a[4], b[2];
            #pragma unroll
            for (int r = 0; r < 4; ++r)
                a[r] = *(const s16x8*)(Ab + (r * 16 + (lane & 15)) * PA + kb);
            #pragma unroll
            for (int q = 0; q < 2; ++q)
                b[q] = *(const s16x8*)(Bb + (wid * 32 + q * 16 + (lane & 15)) * PB + kb);
            #pragma unroll
            for (int r = 0; r < 4; ++r)
                #pragma unroll
                for (int q = 0; q < 2; ++q)
                    acc[r][q] = __builtin_amdgcn_mfma_f32_16x16x32_bf16(a[r], b[q], acc[r][q], 0, 0, 0);
        }
        buf ^= 1; kk += KC;
    }

    __syncthreads();   // all LDS reads done; reuse as gates tile
    #pragma unroll
    for (int r = 0; r < 4; ++r)
        #pragma unroll
        for (int q = 0; q < 2; ++q){
            int gcol = wid * 32 + q * 16 + (lane & 15);
            int grow = r * 16 + (lane >> 4) * 4;
            #pragma unroll
            for (int e = 0; e < 4; ++e)
                gsm[(grow + e) * 132 + gcol] = acc[r][q][e];
        }
    __syncthreads();

    // epilogue: 64 rows x 32 mem-cols per block
    for (int tsk = tid; tsk < 2048; tsk += 256){
        int rl = tsk >> 5, ml = tsk & 31;
        int j = row0 + rl;
        if (j < n){
            int m = blockIdx.y * 32 + ml;
            float iv = gsm[rl * 132 + ml * 4 + 0] + bp[col0 + ml * 4 + 0];
            float fv = gsm[rl * 132 + ml * 4 + 1] + bp[col0 + ml * 4 + 1];
            float gv = gsm[rl * 132 + ml * 4 + 2] + bp[col0 + ml * 4 + 2];
            float ov = gsm[rl * 132 + ml * 4 + 3] + bp[col0 + ml * 4 + 3];
            float chc = 0.f;
            if (!leaf)
                chc = c_below[(size_t)(2*j) * MEM + m] + c_below[(size_t)(2*j+1) * MEM + m];
            float si = 1.f / (1.f + __expf(-iv));
            float sf = 1.f / (1.f + __expf(-fv));
            float so = 1.f / (1.f + __expf(-ov));
            float tg = tanhf(gv);
            float cn = sf * chc + si * tg;
            float hn = so * tanhf(cn);
            c_out[(size_t)j * MEM + m] = cn;
            h_out[(size_t)j * MEM + m] = f2bf(hn);
        }
    }
}

// ---------------- final FC: out[cls] = c_root . W_fc[cls] + b_fc[cls]
__global__ void fc_kernel(const float* __restrict__ c_root, const float* __restrict__ W_fc,
                          const float* __restrict__ b_fc, float* __restrict__ out){
    int lane = threadIdx.x & 63;
    int w = threadIdx.x >> 6;       // 0..3
    for (int cls = w * 3; cls < w * 3 + 3; ++cls){
        float s = 0.f;
        for (int m = lane; m < 256; m += 64)
            s += c_root[m] * W_fc[cls * 256 + m];
        #pragma unroll
        for (int off = 32; off; off >>= 1)
            s += __shfl_down(s, off, 64);
        if (lane == 0) out[cls] = s + b_fc[cls];
    }
}

extern "C" void kernel_launch(void* const* d_in, const int* in_sizes, int n_in,
                              void* d_out, int out_size, void* d_ws, size_t ws_size,
                              hipStream_t stream)
{
    const float* x    = (const float*)d_in[0];
    const float* W_ih = (const float*)d_in[1];
    const float* b_ih = (const float*)d_in[2];
    const float* W_hh = (const float*)d_in[3];
    const float* b_hh = (const float*)d_in[4];
    const float* W_fc = (const float*)d_in[5];
    const float* b_fc = (const float*)d_in[6];
    float* out = (float*)d_out;

    // workspace layout
    const size_t OFF_WP = 0;                       // 1024*384*2      = 786432
    const size_t OFF_BP = 786432;                  // 4096
    const size_t OFF_H0 = 790528;                  // 65536*256*2     = 33554432
    const size_t OFF_H1 = OFF_H0 + 33554432;
    const size_t OFF_C0 = OFF_H1 + 33554432;       // 65536*256*4     = 67108864
    const size_t OFF_C1 = OFF_C0 + 67108864;
    const size_t OFF_A  = OFF_C1 + 67108864;       // 32768*384*2     = 25165824
    const size_t NEEDED = OFF_A + 25165824;
    if (ws_size < NEEDED) return;   // insufficient scratch; fail cleanly

    char* ws = (char*)d_ws;
    unsigned short* Wp = (unsigned short*)(ws + OFF_WP);
    float* bp          = (float*)(ws + OFF_BP);
    unsigned short* h0 = (unsigned short*)(ws + OFF_H0);
    unsigned short* h1 = (unsigned short*)(ws + OFF_H1);
    float* c0          = (float*)(ws + OFF_C0);
    float* c1          = (float*)(ws + OFF_C1);
    unsigned short* Ap = (unsigned short*)(ws + OFF_A);

    pack_w_kernel<<<dim3(1024), dim3(128), 0, stream>>>(W_ih, b_ih, W_hh, b_hh, Wp, bp);

    // ---- leaf level (l = 16): n = 65536, K = 128 (no children)
    pack_leaf_kernel<<<dim3(NLEAF * IN_DIM / 8 / 256), dim3(256), 0, stream>>>(
        x + (size_t)(NLEAF - 1) * IN_DIM, Ap);
    {
        dim3 g(NLEAF / BM, 8);
        gemm_lstm_kernel<<<g, dim3(256), 0, stream>>>(Ap, IN_DIM, NLEAF, IN_DIM,
                                                      Wp, bp, nullptr, 1, c0, h0);
    }

    unsigned short* hprev = h0; float* cprev = c0;
    unsigned short* hcur  = h1; float* ccur  = c1;
    for (int l = 15; l >= 0; --l){
        int n = 1 << l;
        int total = (n * IN_DIM + n * MEM) / 8;
        int blocks = (total + 255) / 256;
        if (blocks > 2048) blocks = 2048;
        pack_level_kernel<<<dim3(blocks), dim3(256), 0, stream>>>(
            n, x + (size_t)(n - 1) * IN_DIM, hprev, Ap);
        dim3 g((n + BM - 1) / BM, 8);
        gemm_lstm_kernel<<<g, dim3(256), 0, stream>>>(Ap, KTOT, n, KTOT,
                                                      Wp, bp, cprev, 0, ccur, hcur);
        unsigned short* ht = hprev; hprev = hcur; hcur = ht;
        float* ct = cprev; cprev = ccur; ccur = ct;
    }

    fc_kernel<<<dim3(1), dim3(256), 0, stream>>>(cprev, W_fc, b_fc, out);
}

// Round 2
// 516.477 us; speedup vs baseline: 1.2305x; 1.2305x over previous
//
#include <hip/hip_runtime.h>
#include <hip/hip_bf16.h>
#include <cstddef>

#define IN_DIM 128
#define MEM 256
#define KTOT 384
#define NLEAF 65536

typedef float f32x4 __attribute__((ext_vector_type(4)));
typedef short s16x8 __attribute__((ext_vector_type(8)));
typedef unsigned int u32;

__device__ inline unsigned short f2bf(float f){
    unsigned int u = __builtin_bit_cast(unsigned int, f);
    u += 0x7fff + ((u >> 16) & 1);
    return (unsigned short)(u >> 16);
}
__device__ inline float bf2f(unsigned short h){
    unsigned int u = ((unsigned int)h) << 16;
    return __builtin_bit_cast(float, u);
}

__device__ inline void gld_lds16(const void* g, void* l){
    __builtin_amdgcn_global_load_lds((const __attribute__((address_space(1))) u32*)g,
                                     (__attribute__((address_space(3))) u32*)l, 16, 0, 0);
}

// ---------------- pack W: Wp[row][k] in ORIGINAL row order (i rows 0-255, f 256-511, g 512-767, o 768-1023)
// k: 0..127 = W_ih, 128..383 = W_hh
__global__ void pack_w_kernel(const float* __restrict__ W_ih, const float* __restrict__ b_ih,
                              const float* __restrict__ W_hh, const float* __restrict__ b_hh,
                              unsigned short* __restrict__ Wp, float* __restrict__ bp){
    int row = blockIdx.x;             // 0..1023
    for (int k = threadIdx.x; k < KTOT; k += blockDim.x){
        float v = (k < IN_DIM) ? W_ih[row * IN_DIM + k] : W_hh[row * MEM + (k - IN_DIM)];
        Wp[row * KTOT + k] = f2bf(v);
    }
    if (threadIdx.x == 0) bp[row] = b_ih[row] + b_hh[row];
}

// ---------------- leaf pack: A[j][k<128] = bf16(x_leaf[j][k]), stride 128
__global__ void pack_leaf_kernel(const float* __restrict__ x_l, unsigned short* __restrict__ A){
    int g = blockIdx.x * blockDim.x + threadIdx.x;   // each handles 8 elems
    size_t base = (size_t)g * 8;
    f32x4 v0 = *(const f32x4*)(x_l + base);
    f32x4 v1 = *(const f32x4*)(x_l + base + 4);
    s16x8 o;
    #pragma unroll
    for (int e = 0; e < 4; ++e){ o[e] = (short)f2bf(v0[e]); o[4+e] = (short)f2bf(v1[e]); }
    *(s16x8*)(A + base) = o;
}

// ---------------- non-leaf pack: A[j][0..127]=x, A[j][128+k]=h_below[2j][k]+h_below[2j+1][k], stride 384
__global__ void pack_level_kernel(int n, const float* __restrict__ x_l,
                                  const unsigned short* __restrict__ h_below,
                                  unsigned short* __restrict__ A){
    int total_x = n * IN_DIM / 8;
    int total_h = n * MEM / 8;
    int total = total_x + total_h;
    for (int g = blockIdx.x * blockDim.x + threadIdx.x; g < total; g += gridDim.x * blockDim.x){
        if (g < total_x){
            int j = g >> 4;             // 16 groups of 8 per 128-wide row
            int ko = (g & 15) * 8;
            const f32x4* s = (const f32x4*)(x_l + (size_t)j * IN_DIM + ko);
            f32x4 v0 = s[0], v1 = s[1];
            s16x8 o;
            #pragma unroll
            for (int e = 0; e < 4; ++e){ o[e] = (short)f2bf(v0[e]); o[4+e] = (short)f2bf(v1[e]); }
            *(s16x8*)(A + (size_t)j * KTOT + ko) = o;
        } else {
            int gh = g - total_x;
            int j = gh >> 5;            // 32 groups of 8 per 256-wide row
            int ko = (gh & 31) * 8;
            s16x8 ha = *(const s16x8*)(h_below + (size_t)(2*j) * MEM + ko);
            s16x8 hb = *(const s16x8*)(h_below + (size_t)(2*j+1) * MEM + ko);
            s16x8 o;
            #pragma unroll
            for (int e = 0; e < 8; ++e)
                o[e] = (short)f2bf(bf2f((unsigned short)ha[e]) + bf2f((unsigned short)hb[e]));
            *(s16x8*)(A + (size_t)j * KTOT + IN_DIM + ko) = o;
        }
    }
}

// ---------------- fused GEMM + LSTM epilogue (m97 structure: global_load_lds, linear LDS, 2-barrier)
// Block: 128 rows x 32 mem columns. Wave (wm,wc): 64 rows x 16 mem.
// Wave's 4 B-fragments = the 4 gates of the same 16 mem cols -> epilogue is pure-register.
#define BM 128
#define KC 64

__global__ __launch_bounds__(256) void gemm_lstm_kernel(
    const unsigned short* __restrict__ A, int lda, int n, int nK,
    const unsigned short* __restrict__ Wp, const float* __restrict__ bp,
    const float* __restrict__ c_below, int leaf,
    float* __restrict__ c_out, unsigned short* __restrict__ h_out)
{
    __shared__ __align__(16) unsigned short As[BM * KC];   // 16 KB, linear [128][64]
    __shared__ __align__(16) unsigned short Bs[BM * KC];   // 16 KB, linear [128][64]; row b -> Wp row (b>>5)*256 + m0 + (b&31)

    const int tid  = threadIdx.x;
    const int lane = tid & 63;
    const int wid  = tid >> 6;
    const int wm   = wid >> 1;            // row half (0,1)
    const int wc   = wid & 1;             // mem half (0,1)
    const int row0 = blockIdx.x * BM;
    const int m0   = blockIdx.y * 32;

    // staging geometry: issue t = wid*4+q covers LDS bytes [t*1024, t*1024+1024)
    // element offset = t*512 + lane*8  ->  tile row = t*8 + (lane>>3), col = (lane&7)*8
    const int srow = lane >> 3;
    const int scol = (lane & 7) * 8;

    f32x4 acc[4][4];
    #pragma unroll
    for (int r = 0; r < 4; ++r)
        #pragma unroll
        for (int q = 0; q < 4; ++q)
            acc[r][q] = (f32x4){0.f, 0.f, 0.f, 0.f};

    const int nIter = nK / KC;
    for (int it = 0; it < nIter; ++it){
        const int kk = it * KC;
        #pragma unroll
        for (int q = 0; q < 4; ++q){
            int t = wid * 4 + q;
            int r = t * 8 + srow;
            gld_lds16(A + (size_t)(row0 + r) * lda + kk + scol, (char*)As + t * 1024);
        }
        #pragma unroll
        for (int q = 0; q < 4; ++q){
            int t = wid * 4 + q;
            int b = t * 8 + srow;
            int grow = (b >> 5) * 256 + m0 + (b & 31);
            gld_lds16(Wp + (size_t)grow * KTOT + kk + scol, (char*)Bs + t * 1024);
        }
        __syncthreads();   // drains vmcnt (global_load_lds) + barrier
        #pragma unroll
        for (int ks = 0; ks < 2; ++ks){
            const int kb = ks * 32 + (lane >> 4) * 8;
            s16x8 a[4], b[4];
            #pragma unroll
            for (int r = 0; r < 4; ++r)
                a[r] = *(const s16x8*)(As + (wm * 64 + r * 16 + (lane & 15)) * KC + kb);
            #pragma unroll
            for (int q = 0; q < 4; ++q)
                b[q] = *(const s16x8*)(Bs + (q * 32 + wc * 16 + (lane & 15)) * KC + kb);
            #pragma unroll
            for (int r = 0; r < 4; ++r)
                #pragma unroll
                for (int q = 0; q < 4; ++q)
                    acc[r][q] = __builtin_amdgcn_mfma_f32_16x16x32_bf16(a[r], b[q], acc[r][q], 0, 0, 0);
        }
        __syncthreads();   // protect LDS before next stage
    }

    // -------- epilogue: lane owns (row j, mem mg) with all 4 gates in acc[r][0..3][e]
    const int mg = m0 + wc * 16 + (lane & 15);
    const float b0 = bp[0 * 256 + mg];
    const float b1 = bp[1 * 256 + mg];
    const float b2 = bp[2 * 256 + mg];
    const float b3 = bp[3 * 256 + mg];
    #pragma unroll
    for (int r = 0; r < 4; ++r){
        #pragma unroll
        for (int e = 0; e < 4; ++e){
            int j = row0 + wm * 64 + r * 16 + (lane >> 4) * 4 + e;
            if (j < n){
                float iv = acc[r][0][e] + b0;
                float fv = acc[r][1][e] + b1;
                float gv = acc[r][2][e] + b2;
                float ov = acc[r][3][e] + b3;
                float chc = 0.f;
                if (!leaf)
                    chc = c_below[(size_t)(2*j) * MEM + mg] + c_below[(size_t)(2*j+1) * MEM + mg];
                float si = 1.f / (1.f + __expf(-iv));
                float sf = 1.f / (1.f + __expf(-fv));
                float so = 1.f / (1.f + __expf(-ov));
                float tg = tanhf(gv);
                float cn = sf * chc + si * tg;
                float hn = so * tanhf(cn);
                c_out[(size_t)j * MEM + mg] = cn;
                h_out[(size_t)j * MEM + mg] = f2bf(hn);
            }
        }
    }
}

// ---------------- final FC: out[cls] = c_root . W_fc[cls] + b_fc[cls]
__global__ void fc_kernel(const float* __restrict__ c_root, const float* __restrict__ W_fc,
                          const float* __restrict__ b_fc, float* __restrict__ out){
    int lane = threadIdx.x & 63;
    int w = threadIdx.x >> 6;       // 0..3
    for (int cls = w * 3; cls < w * 3 + 3; ++cls){
        float s = 0.f;
        for (int m = lane; m < 256; m += 64)
            s += c_root[m] * W_fc[cls * 256 + m];
        #pragma unroll
        for (int off = 32; off; off >>= 1)
            s += __shfl_down(s, off, 64);
        if (lane == 0) out[cls] = s + b_fc[cls];
    }
}

extern "C" void kernel_launch(void* const* d_in, const int* in_sizes, int n_in,
                              void* d_out, int out_size, void* d_ws, size_t ws_size,
                              hipStream_t stream)
{
    const float* x    = (const float*)d_in[0];
    const float* W_ih = (const float*)d_in[1];
    const float* b_ih = (const float*)d_in[2];
    const float* W_hh = (const float*)d_in[3];
    const float* b_hh = (const float*)d_in[4];
    const float* W_fc = (const float*)d_in[5];
    const float* b_fc = (const float*)d_in[6];
    float* out = (float*)d_out;

    // workspace layout
    const size_t OFF_WP = 0;                       // 1024*384*2      = 786432
    const size_t OFF_BP = 786432;                  // 4096
    const size_t OFF_H0 = 790528;                  // 65536*256*2     = 33554432
    const size_t OFF_H1 = OFF_H0 + 33554432;
    const size_t OFF_C0 = OFF_H1 + 33554432;       // 65536*256*4     = 67108864
    const size_t OFF_C1 = OFF_C0 + 67108864;
    const size_t OFF_A  = OFF_C1 + 67108864;       // 32768*384*2     = 25165824 (leaf: 65536*128*2 = same)
    const size_t NEEDED = OFF_A + 25165824;
    if (ws_size < NEEDED) return;   // insufficient scratch; fail cleanly

    char* ws = (char*)d_ws;
    unsigned short* Wp = (unsigned short*)(ws + OFF_WP);
    float* bp          = (float*)(ws + OFF_BP);
    unsigned short* h0 = (unsigned short*)(ws + OFF_H0);
    unsigned short* h1 = (unsigned short*)(ws + OFF_H1);
    float* c0          = (float*)(ws + OFF_C0);
    float* c1          = (float*)(ws + OFF_C1);
    unsigned short* Ap = (unsigned short*)(ws + OFF_A);

    pack_w_kernel<<<dim3(1024), dim3(128), 0, stream>>>(W_ih, b_ih, W_hh, b_hh, Wp, bp);

    // ---- leaf level (l = 16): n = 65536, K = 128 (no children)
    pack_leaf_kernel<<<dim3(NLEAF * IN_DIM / 8 / 256), dim3(256), 0, stream>>>(
        x + (size_t)(NLEAF - 1) * IN_DIM, Ap);
    {
        dim3 g(NLEAF / BM, 8);
        gemm_lstm_kernel<<<g, dim3(256), 0, stream>>>(Ap, IN_DIM, NLEAF, IN_DIM,
                                                      Wp, bp, nullptr, 1, c0, h0);
    }

    unsigned short* hprev = h0; float* cprev = c0;
    unsigned short* hcur  = h1; float* ccur  = c1;
    for (int l = 15; l >= 0; --l){
        int n = 1 << l;
        int total = (n * IN_DIM + n * MEM) / 8;
        int blocks = (total + 255) / 256;
        if (blocks > 2048) blocks = 2048;
        pack_level_kernel<<<dim3(blocks), dim3(256), 0, stream>>>(
            n, x + (size_t)(n - 1) * IN_DIM, hprev, Ap);
        dim3 g((n + BM - 1) / BM, 8);
        gemm_lstm_kernel<<<g, dim3(256), 0, stream>>>(Ap, KTOT, n, KTOT,
                                                      Wp, bp, cprev, 0, ccur, hcur);
        unsigned short* ht = hprev; hprev = hcur; hcur = ht;
        float* ct = cprev; cprev = ccur; ccur = ct;
    }

    fc_kernel<<<dim3(1), dim3(256), 0, stream>>>(cprev, W_fc, b_fc, out);
}

// Round 3
// 381.049 us; speedup vs baseline: 1.6678x; 1.3554x over previous
//
#include <hip/hip_runtime.h>
#include <hip/hip_bf16.h>
#include <cstddef>

#define IN_DIM 128
#define MEM 256
#define KTOT 384
#define NLEAF 65536

typedef float f32x4 __attribute__((ext_vector_type(4)));
typedef short s16x8 __attribute__((ext_vector_type(8)));
typedef unsigned int u32;

__device__ inline unsigned short f2bf(float f){
    unsigned int u = __builtin_bit_cast(unsigned int, f);
    u += 0x7fff + ((u >> 16) & 1);
    return (unsigned short)(u >> 16);
}

__device__ inline void gld_lds16(const void* g, void* l){
    __builtin_amdgcn_global_load_lds((const __attribute__((address_space(1))) u32*)g,
                                     (__attribute__((address_space(3))) u32*)l, 16, 0, 0);
}

__device__ inline float fsigm(float x){
    return __builtin_amdgcn_rcpf(1.f + __expf(-x));
}
__device__ inline float ftanh(float x){
    return 2.f * __builtin_amdgcn_rcpf(1.f + __expf(-2.f * x)) - 1.f;
}

// A-arena element offsets: leaf (l=16) at 0, stride 128; levels 15..0 stride 384.
__host__ __device__ inline size_t offA(int l){
    if (l == 16) return 0;
    return 8388608u + 384u * (65536u - (1u << (l + 1)));
}
#define ARENA_ELEMS 33554048u
#define ARENA_PAD   65536u

// ---------------- pack W: Wp[row][k], original row order; k<128 = W_ih, else W_hh
__global__ void pack_w_kernel(const float* __restrict__ W_ih, const float* __restrict__ b_ih,
                              const float* __restrict__ W_hh, const float* __restrict__ b_hh,
                              unsigned short* __restrict__ Wp, float* __restrict__ bp){
    int row = blockIdx.x;             // 0..1023
    for (int k = threadIdx.x; k < KTOT; k += blockDim.x){
        float v = (k < IN_DIM) ? W_ih[row * IN_DIM + k] : W_hh[row * MEM + (k - IN_DIM)];
        Wp[row * KTOT + k] = f2bf(v);
    }
    if (threadIdx.x == 0) bp[row] = b_ih[row] + b_hh[row];
}

// ---------------- pack ALL x rows (f32 -> bf16) into the per-level A arena
__global__ void pack_x_kernel(const float* __restrict__ x, unsigned short* __restrict__ Aarena){
    const int TOTAL_G = 131071 * 16;   // 8-elem groups
    for (int g = blockIdx.x * blockDim.x + threadIdx.x; g < TOTAL_G; g += gridDim.x * blockDim.x){
        int i  = g >> 4;               // global node row 0..131070
        int ko = (g & 15) * 8;
        int l  = 31 - __clz(i + 1);
        int j  = i + 1 - (1 << l);
        size_t dst = offA(l) + (size_t)j * ((l == 16) ? 128 : 384) + ko;
        const f32x4* s = (const f32x4*)(x + (size_t)i * IN_DIM + ko);
        f32x4 v0 = s[0], v1 = s[1];
        s16x8 o;
        #pragma unroll
        for (int e = 0; e < 4; ++e){ o[e] = (short)f2bf(v0[e]); o[4+e] = (short)f2bf(v1[e]); }
        *(s16x8*)(Aarena + dst) = o;
    }
}

// ---------------- fused GEMM + LSTM + child-pair reduction epilogue
// Block: 128 rows x 32 mem cols. Wave (wm,wc): 64 rows x 16 mem; per-lane all 4 gates.
// Epilogue: lane rows base..base+3 -> parents base/2, base/2+1 (lane-local pair sums).
#define BM 128
#define KC 64

__global__ __launch_bounds__(256) void gemm_lstm_kernel(
    const unsigned short* __restrict__ A, int lda, int n, int nK,
    const unsigned short* __restrict__ Wp, const float* __restrict__ bp,
    const float* __restrict__ csum_in, int leaf,
    unsigned short* __restrict__ A_next, float* __restrict__ csum_out,
    float* __restrict__ c_root, int root)
{
    __shared__ __align__(16) unsigned short As[BM * KC];   // 16 KB linear [128][64]
    __shared__ __align__(16) unsigned short Bs[BM * KC];   // 16 KB linear; row b -> Wp row (b>>5)*256 + m0 + (b&31)

    const int tid  = threadIdx.x;
    const int lane = tid & 63;
    const int wid  = tid >> 6;
    const int wm   = wid >> 1;            // row half
    const int wc   = wid & 1;             // mem half
    const int row0 = blockIdx.x * BM;
    const int m0   = blockIdx.y * 32;

    const int srow = lane >> 3;
    const int scol = (lane & 7) * 8;

    f32x4 acc[4][4];
    #pragma unroll
    for (int r = 0; r < 4; ++r)
        #pragma unroll
        for (int q = 0; q < 4; ++q)
            acc[r][q] = (f32x4){0.f, 0.f, 0.f, 0.f};

    const int nIter = nK / KC;
    for (int it = 0; it < nIter; ++it){
        const int kk = it * KC;
        #pragma unroll
        for (int q = 0; q < 4; ++q){
            int t = wid * 4 + q;
            int r = t * 8 + srow;
            gld_lds16(A + (size_t)(row0 + r) * lda + kk + scol, (char*)As + t * 1024);
        }
        #pragma unroll
        for (int q = 0; q < 4; ++q){
            int t = wid * 4 + q;
            int b = t * 8 + srow;
            int grow = (b >> 5) * 256 + m0 + (b & 31);
            gld_lds16(Wp + (size_t)grow * KTOT + kk + scol, (char*)Bs + t * 1024);
        }
        __syncthreads();
        #pragma unroll
        for (int ks = 0; ks < 2; ++ks){
            const int kb = ks * 32 + (lane >> 4) * 8;
            s16x8 a[4], b[4];
            #pragma unroll
            for (int r = 0; r < 4; ++r)
                a[r] = *(const s16x8*)(As + (wm * 64 + r * 16 + (lane & 15)) * KC + kb);
            #pragma unroll
            for (int q = 0; q < 4; ++q)
                b[q] = *(const s16x8*)(Bs + (q * 32 + wc * 16 + (lane & 15)) * KC + kb);
            #pragma unroll
            for (int r = 0; r < 4; ++r)
                #pragma unroll
                for (int q = 0; q < 4; ++q)
                    acc[r][q] = __builtin_amdgcn_mfma_f32_16x16x32_bf16(a[r], b[q], acc[r][q], 0, 0, 0);
        }
        __syncthreads();
    }

    // -------- epilogue
    const int mg = m0 + wc * 16 + (lane & 15);
    const float b0 = bp[0 * 256 + mg];
    const float b1 = bp[1 * 256 + mg];
    const float b2 = bp[2 * 256 + mg];
    const float b3 = bp[3 * 256 + mg];
    #pragma unroll
    for (int r = 0; r < 4; ++r){
        const int base = row0 + wm * 64 + r * 16 + (lane >> 4) * 4;
        float cn[4], hn[4];
        #pragma unroll
        for (int e = 0; e < 4; ++e){
            int j = base + e;
            if (j < n){
                float iv = acc[r][0][e] + b0;
                float fv = acc[r][1][e] + b1;
                float gv = acc[r][2][e] + b2;
                float ov = acc[r][3][e] + b3;
                float chc = leaf ? 0.f : csum_in[(size_t)j * MEM + mg];
                float c  = fsigm(fv) * chc + fsigm(iv) * ftanh(gv);
                cn[e] = c;
                hn[e] = fsigm(ov) * ftanh(c);
            } else { cn[e] = 0.f; hn[e] = 0.f; }
        }
        if (root){
            if (base == 0) c_root[mg] = cn[0];
        } else {
            if (base < n){
                int p0 = base >> 1;
                A_next[(size_t)p0 * KTOT + IN_DIM + mg] = f2bf(hn[0] + hn[1]);
                csum_out[(size_t)p0 * MEM + mg] = cn[0] + cn[1];
            }
            if (base + 2 < n){
                int p1 = (base >> 1) + 1;
                A_next[(size_t)p1 * KTOT + IN_DIM + mg] = f2bf(hn[2] + hn[3]);
                csum_out[(size_t)p1 * MEM + mg] = cn[2] + cn[3];
            }
        }
    }
}

// ---------------- final FC
__global__ void fc_kernel(const float* __restrict__ c_root, const float* __restrict__ W_fc,
                          const float* __restrict__ b_fc, float* __restrict__ out){
    int lane = threadIdx.x & 63;
    int w = threadIdx.x >> 6;       // 0..3
    for (int cls = w * 3; cls < w * 3 + 3; ++cls){
        float s = 0.f;
        for (int m = lane; m < 256; m += 64)
            s += c_root[m] * W_fc[cls * 256 + m];
        #pragma unroll
        for (int off = 32; off; off >>= 1)
            s += __shfl_down(s, off, 64);
        if (lane == 0) out[cls] = s + b_fc[cls];
    }
}

extern "C" void kernel_launch(void* const* d_in, const int* in_sizes, int n_in,
                              void* d_out, int out_size, void* d_ws, size_t ws_size,
                              hipStream_t stream)
{
    const float* x    = (const float*)d_in[0];
    const float* W_ih = (const float*)d_in[1];
    const float* b_ih = (const float*)d_in[2];
    const float* W_hh = (const float*)d_in[3];
    const float* b_hh = (const float*)d_in[4];
    const float* W_fc = (const float*)d_in[5];
    const float* b_fc = (const float*)d_in[6];
    float* out = (float*)d_out;

    // workspace layout (bytes)
    const size_t OFF_WP = 0;                                   // 786432
    const size_t OFF_BP = 786432;                              // 4096
    const size_t OFF_A  = 790528;                              // (33554048+65536)*2 = 67239168
    const size_t OFF_CS0 = OFF_A + (size_t)(ARENA_ELEMS + ARENA_PAD) * 2;   // 33554432
    const size_t OFF_CS1 = OFF_CS0 + 33554432;                 // 33554432
    const size_t OFF_CR  = OFF_CS1 + 33554432;                 // 1024
    const size_t NEEDED  = OFF_CR + 1024;
    if (ws_size < NEEDED) return;

    char* ws = (char*)d_ws;
    unsigned short* Wp    = (unsigned short*)(ws + OFF_WP);
    float* bp             = (float*)(ws + OFF_BP);
    unsigned short* arena = (unsigned short*)(ws + OFF_A);
    float* cs0            = (float*)(ws + OFF_CS0);
    float* cs1            = (float*)(ws + OFF_CS1);
    float* c_root         = (float*)(ws + OFF_CR);

    pack_w_kernel<<<dim3(1024), dim3(128), 0, stream>>>(W_ih, b_ih, W_hh, b_hh, Wp, bp);
    pack_x_kernel<<<dim3(2048), dim3(256), 0, stream>>>(x, arena);

    // ---- leaf level (l=16): n=65536, K=128; writes hsum into A(15), csum into cs0
    gemm_lstm_kernel<<<dim3(NLEAF / BM, 8), dim3(256), 0, stream>>>(
        arena + offA(16), IN_DIM, NLEAF, IN_DIM, Wp, bp,
        nullptr, 1, arena + offA(15), cs0, nullptr, 0);

    float* cs_in = cs0; float* cs_out = cs1;
    for (int l = 15; l >= 1; --l){
        int n = 1 << l;
        gemm_lstm_kernel<<<dim3((n + BM - 1) / BM, 8), dim3(256), 0, stream>>>(
            arena + offA(l), KTOT, n, KTOT, Wp, bp,
            cs_in, 0, arena + offA(l - 1), cs_out, nullptr, 0);
        float* t = cs_in; cs_in = cs_out; cs_out = t;
    }
    // ---- root (l=0): n=1
    gemm_lstm_kernel<<<dim3(1, 8), dim3(256), 0, stream>>>(
        arena + offA(0), KTOT, 1, KTOT, Wp, bp,
        cs_in, 0, nullptr, nullptr, c_root, 1);

    fc_kernel<<<dim3(1), dim3(256), 0, stream>>>(c_root, W_fc, b_fc, out);
}

// Round 4
// 335.723 us; speedup vs baseline: 1.8930x; 1.1350x over previous
//
#include <hip/hip_runtime.h>
#include <hip/hip_bf16.h>
#include <cstddef>

#define IN_DIM 128
#define MEM 256
#define KTOT 384
#define NLEAF 65536

typedef float f32x4 __attribute__((ext_vector_type(4)));
typedef short s16x8 __attribute__((ext_vector_type(8)));
typedef unsigned int u32;

__device__ inline unsigned short f2bf(float f){
    unsigned int u = __builtin_bit_cast(unsigned int, f);
    u += 0x7fff + ((u >> 16) & 1);
    return (unsigned short)(u >> 16);
}

__device__ inline void gld_lds16(const void* g, void* l){
    __builtin_amdgcn_global_load_lds((const __attribute__((address_space(1))) u32*)g,
                                     (__attribute__((address_space(3))) u32*)l, 16, 0, 0);
}

__device__ inline float fsigm(float x){
    return __builtin_amdgcn_rcpf(1.f + __expf(-x));
}
__device__ inline float ftanh(float x){
    return 2.f * __builtin_amdgcn_rcpf(1.f + __expf(-2.f * x)) - 1.f;
}

// A-arena element offsets: leaf (l=16) at 0, stride 128; levels 15..0 stride 384.
__host__ __device__ inline size_t offA(int l){
    if (l == 16) return 0;
    return 8388608u + 384u * (65536u - (1u << (l + 1)));
}
#define ARENA_ELEMS 33554048u
#define ARENA_PAD   65536u

// ---------------- pack W: Wp[row][k], original row order; k<128 = W_ih, else W_hh
__global__ void pack_w_kernel(const float* __restrict__ W_ih, const float* __restrict__ b_ih,
                              const float* __restrict__ W_hh, const float* __restrict__ b_hh,
                              unsigned short* __restrict__ Wp, float* __restrict__ bp){
    int row = blockIdx.x;             // 0..1023
    for (int k = threadIdx.x; k < KTOT; k += blockDim.x){
        float v = (k < IN_DIM) ? W_ih[row * IN_DIM + k] : W_hh[row * MEM + (k - IN_DIM)];
        Wp[row * KTOT + k] = f2bf(v);
    }
    if (threadIdx.x == 0) bp[row] = b_ih[row] + b_hh[row];
}

// ---------------- pack ALL x rows (f32 -> bf16) into the per-level A arena
__global__ void pack_x_kernel(const float* __restrict__ x, unsigned short* __restrict__ Aarena){
    const int TOTAL_G = 131071 * 16;   // 8-elem groups
    for (int g = blockIdx.x * blockDim.x + threadIdx.x; g < TOTAL_G; g += gridDim.x * blockDim.x){
        int i  = g >> 4;               // global node row 0..131070
        int ko = (g & 15) * 8;
        int l  = 31 - __clz(i + 1);
        int j  = i + 1 - (1 << l);
        size_t dst = offA(l) + (size_t)j * ((l == 16) ? 128 : 384) + ko;
        const f32x4* s = (const f32x4*)(x + (size_t)i * IN_DIM + ko);
        f32x4 v0 = s[0], v1 = s[1];
        s16x8 o;
        #pragma unroll
        for (int e = 0; e < 4; ++e){ o[e] = (short)f2bf(v0[e]); o[4+e] = (short)f2bf(v1[e]); }
        *(s16x8*)(Aarena + dst) = o;
    }
}

// ---------------- fused GEMM + LSTM + child-pair reduction epilogue
// Block: 128 rows x 32 mem cols. Wave (wm,wc): 64 rows x 16 mem; per-lane all 4 gates.
// Double-buffered LDS, counted vmcnt(8) (8 global_load_lds per wave per tile).
#define BM 128
#define KC 64

template<int NK>
__global__ __launch_bounds__(256) void gemm_lstm_kernel(
    const unsigned short* __restrict__ A, int n,
    const unsigned short* __restrict__ Wp, const float* __restrict__ bp,
    const float* __restrict__ csum_in, int leaf,
    unsigned short* __restrict__ A_next, float* __restrict__ csum_out,
    float* __restrict__ c_root, int root)
{
    __shared__ __align__(16) unsigned short As[2][BM * KC];   // 2 x 16 KB
    __shared__ __align__(16) unsigned short Bs[2][BM * KC];   // 2 x 16 KB

    const int tid  = threadIdx.x;
    const int lane = tid & 63;
    const int wid  = tid >> 6;
    const int wm   = wid >> 1;            // row half
    const int wc   = wid & 1;             // mem half
    const int row0 = blockIdx.x * BM;
    const int m0   = blockIdx.y * 32;

    const int srow = lane >> 3;
    const int scol = (lane & 7) * 8;

    f32x4 acc[4][4];
    #pragma unroll
    for (int r = 0; r < 4; ++r)
        #pragma unroll
        for (int q = 0; q < 4; ++q)
            acc[r][q] = (f32x4){0.f, 0.f, 0.f, 0.f};

    auto stage = [&](int d, int kk){
        char* asb = (char*)As[d];
        char* bsb = (char*)Bs[d];
        #pragma unroll
        for (int q = 0; q < 4; ++q){
            int t = wid * 4 + q;
            int r = t * 8 + srow;
            gld_lds16(A + (size_t)(row0 + r) * NK + kk + scol, asb + t * 1024);
        }
        #pragma unroll
        for (int q = 0; q < 4; ++q){
            int t = wid * 4 + q;
            int b = t * 8 + srow;
            int grow = (b >> 5) * 256 + m0 + (b & 31);
            gld_lds16(Wp + (size_t)grow * KTOT + kk + scol, bsb + t * 1024);
        }
    };

    constexpr int nIter = NK / KC;
    stage(0, 0);
    int buf = 0;
    #pragma unroll
    for (int it = 0; it < nIter; ++it){
        if (it + 1 < nIter){
            stage(buf ^ 1, (it + 1) * KC);
            asm volatile("s_waitcnt vmcnt(8)" ::: "memory");   // current tile's 8 loads done; next 8 in flight
        } else {
            asm volatile("s_waitcnt vmcnt(0)" ::: "memory");
        }
        __builtin_amdgcn_s_barrier();
        const unsigned short* Ab = As[buf];
        const unsigned short* Bb = Bs[buf];
        #pragma unroll
        for (int ks = 0; ks < 2; ++ks){
            const int kb = ks * 32 + (lane >> 4) * 8;
            s16x8 a[4], b[4];
            #pragma unroll
            for (int r = 0; r < 4; ++r)
                a[r] = *(const s16x8*)(Ab + (wm * 64 + r * 16 + (lane & 15)) * KC + kb);
            #pragma unroll
            for (int q = 0; q < 4; ++q)
                b[q] = *(const s16x8*)(Bb + (q * 32 + wc * 16 + (lane & 15)) * KC + kb);
            #pragma unroll
            for (int r = 0; r < 4; ++r)
                #pragma unroll
                for (int q = 0; q < 4; ++q)
                    acc[r][q] = __builtin_amdgcn_mfma_f32_16x16x32_bf16(a[r], b[q], acc[r][q], 0, 0, 0);
        }
        __builtin_amdgcn_s_barrier();   // all waves done reading buf before it is restaged
        buf ^= 1;
    }

    // -------- epilogue
    const int mg = m0 + wc * 16 + (lane & 15);
    const float b0 = bp[0 * 256 + mg];
    const float b1 = bp[1 * 256 + mg];
    const float b2 = bp[2 * 256 + mg];
    const float b3 = bp[3 * 256 + mg];
    #pragma unroll
    for (int r = 0; r < 4; ++r){
        const int base = row0 + wm * 64 + r * 16 + (lane >> 4) * 4;
        float cn[4], hn[4];
        #pragma unroll
        for (int e = 0; e < 4; ++e){
            int j = base + e;
            if (j < n){
                float iv = acc[r][0][e] + b0;
                float fv = acc[r][1][e] + b1;
                float gv = acc[r][2][e] + b2;
                float ov = acc[r][3][e] + b3;
                float chc = leaf ? 0.f : csum_in[(size_t)j * MEM + mg];
                float c  = fsigm(fv) * chc + fsigm(iv) * ftanh(gv);
                cn[e] = c;
                hn[e] = fsigm(ov) * ftanh(c);
            } else { cn[e] = 0.f; hn[e] = 0.f; }
        }
        if (root){
            if (base == 0) c_root[mg] = cn[0];
        } else {
            if (base < n){
                int p0 = base >> 1;
                A_next[(size_t)p0 * KTOT + IN_DIM + mg] = f2bf(hn[0] + hn[1]);
                csum_out[(size_t)p0 * MEM + mg] = cn[0] + cn[1];
            }
            if (base + 2 < n){
                int p1 = (base >> 1) + 1;
                A_next[(size_t)p1 * KTOT + IN_DIM + mg] = f2bf(hn[2] + hn[3]);
                csum_out[(size_t)p1 * MEM + mg] = cn[2] + cn[3];
            }
        }
    }
}

// ---------------- final FC
__global__ void fc_kernel(const float* __restrict__ c_root, const float* __restrict__ W_fc,
                          const float* __restrict__ b_fc, float* __restrict__ out){
    int lane = threadIdx.x & 63;
    int w = threadIdx.x >> 6;       // 0..3
    for (int cls = w * 3; cls < w * 3 + 3; ++cls){
        float s = 0.f;
        for (int m = lane; m < 256; m += 64)
            s += c_root[m] * W_fc[cls * 256 + m];
        #pragma unroll
        for (int off = 32; off; off >>= 1)
            s += __shfl_down(s, off, 64);
        if (lane == 0) out[cls] = s + b_fc[cls];
    }
}

extern "C" void kernel_launch(void* const* d_in, const int* in_sizes, int n_in,
                              void* d_out, int out_size, void* d_ws, size_t ws_size,
                              hipStream_t stream)
{
    const float* x    = (const float*)d_in[0];
    const float* W_ih = (const float*)d_in[1];
    const float* b_ih = (const float*)d_in[2];
    const float* W_hh = (const float*)d_in[3];
    const float* b_hh = (const float*)d_in[4];
    const float* W_fc = (const float*)d_in[5];
    const float* b_fc = (const float*)d_in[6];
    float* out = (float*)d_out;

    // workspace layout (bytes)
    const size_t OFF_WP = 0;                                   // 786432
    const size_t OFF_BP = 786432;                              // 4096
    const size_t OFF_A  = 790528;                              // (33554048+65536)*2
    const size_t OFF_CS0 = OFF_A + (size_t)(ARENA_ELEMS + ARENA_PAD) * 2;   // 33554432
    const size_t OFF_CS1 = OFF_CS0 + 33554432;                 // 33554432
    const size_t OFF_CR  = OFF_CS1 + 33554432;                 // 1024
    const size_t NEEDED  = OFF_CR + 1024;
    if (ws_size < NEEDED) return;

    char* ws = (char*)d_ws;
    unsigned short* Wp    = (unsigned short*)(ws + OFF_WP);
    float* bp             = (float*)(ws + OFF_BP);
    unsigned short* arena = (unsigned short*)(ws + OFF_A);
    float* cs0            = (float*)(ws + OFF_CS0);
    float* cs1            = (float*)(ws + OFF_CS1);
    float* c_root         = (float*)(ws + OFF_CR);

    pack_w_kernel<<<dim3(1024), dim3(128), 0, stream>>>(W_ih, b_ih, W_hh, b_hh, Wp, bp);
    pack_x_kernel<<<dim3(2048), dim3(256), 0, stream>>>(x, arena);

    // ---- leaf level (l=16): n=65536, K=128; writes hsum into A(15), csum into cs0
    gemm_lstm_kernel<IN_DIM><<<dim3(NLEAF / BM, 8), dim3(256), 0, stream>>>(
        arena + offA(16), NLEAF, Wp, bp,
        nullptr, 1, arena + offA(15), cs0, nullptr, 0);

    float* cs_in = cs0; float* cs_out = cs1;
    for (int l = 15; l >= 1; --l){
        int n = 1 << l;
        gemm_lstm_kernel<KTOT><<<dim3((n + BM - 1) / BM, 8), dim3(256), 0, stream>>>(
            arena + offA(l), n, Wp, bp,
            cs_in, 0, arena + offA(l - 1), cs_out, nullptr, 0);
        float* t = cs_in; cs_in = cs_out; cs_out = t;
    }
    // ---- root (l=0): n=1
    gemm_lstm_kernel<KTOT><<<dim3(1, 8), dim3(256), 0, stream>>>(
        arena + offA(0), 1, Wp, bp,
        cs_in, 0, nullptr, nullptr, c_root, 1);

    fc_kernel<<<dim3(1), dim3(256), 0, stream>>>(c_root, W_fc, b_fc, out);
}

// Round 5
// 247.339 us; speedup vs baseline: 2.5694x; 1.3573x over previous
//
#include <hip/hip_runtime.h>
#include <hip/hip_bf16.h>
#include <cstddef>

#define IN_DIM 128
#define MEM 256
#define KTOT 384
#define NLEAF 65536

typedef float f32x4 __attribute__((ext_vector_type(4)));
typedef short s16x8 __attribute__((ext_vector_type(8)));
typedef unsigned int u32;

__device__ inline unsigned short f2bf(float f){
    unsigned int u = __builtin_bit_cast(unsigned int, f);
    u += 0x7fff + ((u >> 16) & 1);
    return (unsigned short)(u >> 16);
}

__device__ inline void gld_lds16(const void* g, void* l){
    __builtin_amdgcn_global_load_lds((const __attribute__((address_space(1))) u32*)g,
                                     (__attribute__((address_space(3))) u32*)l, 16, 0, 0);
}

__device__ inline float fsigm(float x){
    return __builtin_amdgcn_rcpf(1.f + __expf(-x));
}
__device__ inline float ftanh(float x){
    return 2.f * __builtin_amdgcn_rcpf(1.f + __expf(-2.f * x)) - 1.f;
}

// A-arena element offsets: leaf (l=16) at 0, stride 128; levels 15..0 stride 384.
__host__ __device__ inline size_t offA(int l){
    if (l == 16) return 0;
    return 8388608u + 384u * (65536u - (1u << (l + 1)));
}
#define ARENA_ELEMS 33554048u
#define ARENA_PAD   65536u

// ---------------- pack W: Wp[row][k], original row order; k<128 = W_ih, else W_hh
__global__ void pack_w_kernel(const float* __restrict__ W_ih, const float* __restrict__ b_ih,
                              const float* __restrict__ W_hh, const float* __restrict__ b_hh,
                              unsigned short* __restrict__ Wp, float* __restrict__ bp){
    int row = blockIdx.x;             // 0..1023
    for (int k = threadIdx.x; k < KTOT; k += blockDim.x){
        float v = (k < IN_DIM) ? W_ih[row * IN_DIM + k] : W_hh[row * MEM + (k - IN_DIM)];
        Wp[row * KTOT + k] = f2bf(v);
    }
    if (threadIdx.x == 0) bp[row] = b_ih[row] + b_hh[row];
}

// ---------------- pack ALL x rows (f32 -> bf16) into the per-level A arena
__global__ void pack_x_kernel(const float* __restrict__ x, unsigned short* __restrict__ Aarena){
    const int TOTAL_G = 131071 * 16;   // 8-elem groups
    for (int g = blockIdx.x * blockDim.x + threadIdx.x; g < TOTAL_G; g += gridDim.x * blockDim.x){
        int i  = g >> 4;               // global node row 0..131070
        int ko = (g & 15) * 8;
        int l  = 31 - __clz(i + 1);
        int j  = i + 1 - (1 << l);
        size_t dst = offA(l) + (size_t)j * ((l == 16) ? 128 : 384) + ko;
        const f32x4* s = (const f32x4*)(x + (size_t)i * IN_DIM + ko);
        f32x4 v0 = s[0], v1 = s[1];
        s16x8 o;
        #pragma unroll
        for (int e = 0; e < 4; ++e){ o[e] = (short)f2bf(v0[e]); o[4+e] = (short)f2bf(v1[e]); }
        *(s16x8*)(Aarena + dst) = o;
    }
}

// ---------------- fused GEMM + LSTM + child-pair reduction epilogue
// Block: 128 rows x 32 mem cols. Wave (wm,wc): 64 rows x 16 mem; per-lane all 4 gates.
// Double-buffered LDS, counted vmcnt(8).
// T2 XOR-swizzle (rule #21 both-sides): LDS dest linear (global_load_lds),
// global SOURCE column permuted by slot ^= srow, READ slot ^= (row&7)=lane&7.
// Slot space = 3 bits (KC=64 bf16 = 8 x 16B slots), so XOR permutes cleanly.
#define BM 128
#define KC 64

template<int NK>
__global__ __launch_bounds__(256) void gemm_lstm_kernel(
    const unsigned short* __restrict__ A, int n,
    const unsigned short* __restrict__ Wp, const float* __restrict__ bp,
    const float* __restrict__ csum_in, int leaf,
    unsigned short* __restrict__ A_next, float* __restrict__ csum_out,
    float* __restrict__ c_root, int root)
{
    __shared__ __align__(16) unsigned short As[2][BM * KC];   // 2 x 16 KB
    __shared__ __align__(16) unsigned short Bs[2][BM * KC];   // 2 x 16 KB

    const int tid  = threadIdx.x;
    const int lane = tid & 63;
    const int wid  = tid >> 6;
    const int wm   = wid >> 1;            // row half
    const int wc   = wid & 1;             // mem half
    const int row0 = blockIdx.x * BM;
    const int m0   = blockIdx.y * 32;

    const int srow = lane >> 3;                              // 0..7
    const int scol = ((lane & 7) ^ srow) * 8;                // swizzled source slot

    const int mg = m0 + wc * 16 + (lane & 15);

    // ---- prefetch epilogue operands (hidden under the K-loop)
    const float b0 = bp[0 * 256 + mg];
    const float b1 = bp[1 * 256 + mg];
    const float b2 = bp[2 * 256 + mg];
    const float b3 = bp[3 * 256 + mg];
    float cpre[4][4];
    if (!leaf){
        #pragma unroll
        for (int r = 0; r < 4; ++r){
            const int base = row0 + wm * 64 + r * 16 + (lane >> 4) * 4;
            #pragma unroll
            for (int e = 0; e < 4; ++e)
                cpre[r][e] = csum_in[(size_t)(base + e) * MEM + mg];  // always in-allocation
        }
    } else {
        #pragma unroll
        for (int r = 0; r < 4; ++r)
            #pragma unroll
            for (int e = 0; e < 4; ++e) cpre[r][e] = 0.f;
    }

    f32x4 acc[4][4];
    #pragma unroll
    for (int r = 0; r < 4; ++r)
        #pragma unroll
        for (int q = 0; q < 4; ++q)
            acc[r][q] = (f32x4){0.f, 0.f, 0.f, 0.f};

    auto stage = [&](int d, int kk){
        char* asb = (char*)As[d];
        char* bsb = (char*)Bs[d];
        #pragma unroll
        for (int q = 0; q < 4; ++q){
            int t = wid * 4 + q;
            int r = t * 8 + srow;
            gld_lds16(A + (size_t)(row0 + r) * NK + kk + scol, asb + t * 1024);
        }
        #pragma unroll
        for (int q = 0; q < 4; ++q){
            int t = wid * 4 + q;
            int b = t * 8 + srow;
            int grow = (b >> 5) * 256 + m0 + (b & 31);
            gld_lds16(Wp + (size_t)grow * KTOT + kk + scol, bsb + t * 1024);
        }
    };

    constexpr int nIter = NK / KC;
    stage(0, 0);
    int buf = 0;
    #pragma unroll
    for (int it = 0; it < nIter; ++it){
        if (it + 1 < nIter){
            stage(buf ^ 1, (it + 1) * KC);
            asm volatile("s_waitcnt vmcnt(8)" ::: "memory");   // current tile done; next 8 in flight
        } else {
            asm volatile("s_waitcnt vmcnt(0)" ::: "memory");
        }
        __builtin_amdgcn_s_barrier();
        const unsigned short* Ab = As[buf];
        const unsigned short* Bb = Bs[buf];
        #pragma unroll
        for (int ks = 0; ks < 2; ++ks){
            const int slot = ks * 4 + (lane >> 4);
            const int kb = (slot ^ (lane & 7)) * 8;            // swizzled read slot
            s16x8 a[4], b[4];
            #pragma unroll
            for (int r = 0; r < 4; ++r)
                a[r] = *(const s16x8*)(Ab + (wm * 64 + r * 16 + (lane & 15)) * KC + kb);
            #pragma unroll
            for (int q = 0; q < 4; ++q)
                b[q] = *(const s16x8*)(Bb + (q * 32 + wc * 16 + (lane & 15)) * KC + kb);
            #pragma unroll
            for (int r = 0; r < 4; ++r)
                #pragma unroll
                for (int q = 0; q < 4; ++q)
                    acc[r][q] = __builtin_amdgcn_mfma_f32_16x16x32_bf16(a[r], b[q], acc[r][q], 0, 0, 0);
        }
        __builtin_amdgcn_s_barrier();   // all waves done reading buf before restage
        buf ^= 1;
    }

    // -------- epilogue
    #pragma unroll
    for (int r = 0; r < 4; ++r){
        const int base = row0 + wm * 64 + r * 16 + (lane >> 4) * 4;
        float cn[4], hn[4];
        #pragma unroll
        for (int e = 0; e < 4; ++e){
            int j = base + e;
            float iv = acc[r][0][e] + b0;
            float fv = acc[r][1][e] + b1;
            float gv = acc[r][2][e] + b2;
            float ov = acc[r][3][e] + b3;
            float c  = fsigm(fv) * cpre[r][e] + fsigm(iv) * ftanh(gv);
            cn[e] = c;
            hn[e] = fsigm(ov) * ftanh(c);
            (void)j;
        }
        if (root){
            if (base == 0) c_root[mg] = cn[0];
        } else {
            if (base < n){
                int p0 = base >> 1;
                A_next[(size_t)p0 * KTOT + IN_DIM + mg] = f2bf(hn[0] + hn[1]);
                csum_out[(size_t)p0 * MEM + mg] = cn[0] + cn[1];
            }
            if (base + 2 < n){
                int p1 = (base >> 1) + 1;
                A_next[(size_t)p1 * KTOT + IN_DIM + mg] = f2bf(hn[2] + hn[3]);
                csum_out[(size_t)p1 * MEM + mg] = cn[2] + cn[3];
            }
        }
    }
}

// ---------------- final FC
__global__ void fc_kernel(const float* __restrict__ c_root, const float* __restrict__ W_fc,
                          const float* __restrict__ b_fc, float* __restrict__ out){
    int lane = threadIdx.x & 63;
    int w = threadIdx.x >> 6;       // 0..3
    for (int cls = w * 3; cls < w * 3 + 3; ++cls){
        float s = 0.f;
        for (int m = lane; m < 256; m += 64)
            s += c_root[m] * W_fc[cls * 256 + m];
        #pragma unroll
        for (int off = 32; off; off >>= 1)
            s += __shfl_down(s, off, 64);
        if (lane == 0) out[cls] = s + b_fc[cls];
    }
}

extern "C" void kernel_launch(void* const* d_in, const int* in_sizes, int n_in,
                              void* d_out, int out_size, void* d_ws, size_t ws_size,
                              hipStream_t stream)
{
    const float* x    = (const float*)d_in[0];
    const float* W_ih = (const float*)d_in[1];
    const float* b_ih = (const float*)d_in[2];
    const float* W_hh = (const float*)d_in[3];
    const float* b_hh = (const float*)d_in[4];
    const float* W_fc = (const float*)d_in[5];
    const float* b_fc = (const float*)d_in[6];
    float* out = (float*)d_out;

    // workspace layout (bytes)
    const size_t OFF_WP = 0;                                   // 786432
    const size_t OFF_BP = 786432;                              // 4096
    const size_t OFF_A  = 790528;                              // (33554048+65536)*2
    const size_t OFF_CS0 = OFF_A + (size_t)(ARENA_ELEMS + ARENA_PAD) * 2;   // 33554432
    const size_t OFF_CS1 = OFF_CS0 + 33554432;                 // 33554432
    const size_t OFF_CR  = OFF_CS1 + 33554432;                 // 1024
    const size_t NEEDED  = OFF_CR + 1024;
    if (ws_size < NEEDED) return;

    char* ws = (char*)d_ws;
    unsigned short* Wp    = (unsigned short*)(ws + OFF_WP);
    float* bp             = (float*)(ws + OFF_BP);
    unsigned short* arena = (unsigned short*)(ws + OFF_A);
    float* cs0            = (float*)(ws + OFF_CS0);
    float* cs1            = (float*)(ws + OFF_CS1);
    float* c_root         = (float*)(ws + OFF_CR);

    pack_w_kernel<<<dim3(1024), dim3(128), 0, stream>>>(W_ih, b_ih, W_hh, b_hh, Wp, bp);
    pack_x_kernel<<<dim3(2048), dim3(256), 0, stream>>>(x, arena);

    // ---- leaf level (l=16): n=65536, K=128; writes hsum into A(15), csum into cs0
    gemm_lstm_kernel<IN_DIM><<<dim3(NLEAF / BM, 8), dim3(256), 0, stream>>>(
        arena + offA(16), NLEAF, Wp, bp,
        nullptr, 1, arena + offA(15), cs0, nullptr, 0);

    float* cs_in = cs0; float* cs_out = cs1;
    for (int l = 15; l >= 1; --l){
        int n = 1 << l;
        gemm_lstm_kernel<KTOT><<<dim3((n + BM - 1) / BM, 8), dim3(256), 0, stream>>>(
            arena + offA(l), n, Wp, bp,
            cs_in, 0, arena + offA(l - 1), cs_out, nullptr, 0);
        float* t = cs_in; cs_in = cs_out; cs_out = t;
    }
    // ---- root (l=0): n=1
    gemm_lstm_kernel<KTOT><<<dim3(1, 8), dim3(256), 0, stream>>>(
        arena + offA(0), 1, Wp, bp,
        cs_in, 0, nullptr, nullptr, c_root, 1);

    fc_kernel<<<dim3(1), dim3(256), 0, stream>>>(c_root, W_fc, b_fc, out);
}